// Round 7
// baseline (14239.825 us; speedup 1.0000x reference)
//
#include <hip/hip_runtime.h>

#define BB 256
#define NN 512
#define DD 128
#define HH 8

static constexpr float NEGC = -1e9f;
static constexpr float INV_SQRT_D = 0.08838834764831845f; // 1/sqrt(128)

__device__ __forceinline__ float dot4(float4 a, float4 b) {
    return a.x * b.x + a.y * b.y + a.z * b.z + a.w * b.w;
}
__device__ __forceinline__ void fma4(float4& a, float p, float4 e) {
    a.x += p * e.x; a.y += p * e.y; a.z += p * e.z; a.w += p * e.w;
}

#define FOR16(OP) OP(0) OP(1) OP(2) OP(3) OP(4) OP(5) OP(6) OP(7) \
                  OP(8) OP(9) OP(10) OP(11) OP(12) OP(13) OP(14) OP(15)

// ---------------- precompute: fixed_ctx = mean_n(E) @ W_fixed ----------------
__global__ __launch_bounds__(128)
void precompute_fc(const float* __restrict__ E, const float* __restrict__ Wf,
                   float* __restrict__ fc) {
    int b = blockIdx.x, d = threadIdx.x;
    __shared__ float ge[DD];
    const float* Eb = E + (size_t)b * NN * DD;
    float s = 0.f;
    for (int n = 0; n < NN; ++n) s += Eb[n * DD + d];
    ge[d] = s * (1.0f / 512.0f);
    __syncthreads();
    float o = 0.f;
    for (int k = 0; k < DD; ++k) o += ge[k] * Wf[k * DD + d];
    fc[b * DD + d] = o;
}

// ---- precompute: WkT[k][d] = W_node[d][k] (k<128);  W_og = W_out @ Wl^T ----
__global__ __launch_bounds__(128)
void precompute_w(const float* __restrict__ Wn, const float* __restrict__ Wout,
                  float* __restrict__ Wog, float* __restrict__ WkT) {
    int k = blockIdx.x, d = threadIdx.x;
    WkT[k * DD + d] = Wn[d * 384 + k];
    float s = 0.f;
    for (int e = 0; e < DD; ++e) s += Wout[k * DD + e] * Wn[d * 384 + 256 + e];
    Wog[k * DD + d] = s;
}

// ---------------------------- main decoder ----------------------------------
// 512 threads = 1 thread per row. Row lo-half (quads 0..15) in 16 NAMED float4
// (64 VGPR; empirical budget at 512thr = 128, demand ~110 -> resident).
// Row hi-half (quads 16..31) permanently in LDS Ehi, col-swizzled (c^(n&15)).
// e-bar's lo-half transposed access reads global E (L2/L3-resident, static).
// LDS 160,176 B.
struct SMw {
    float Ehi[NN * 64];    // 131072: row n, quads 16..31 at col (c^(n&15))
    float P[HH][520];      // 16640: bank-staggered; aliased as pw[4][8][128]
    float qt[HH][DD];      // 4096
    float eb[HH][DD];      // 4096
    float part[4][DD];     // 2048: phase0/2 scratch; aliased as lgp[512]
    float curE[64];        // lo half of current row
    float qarr[DD];        // q, later g~
    float fcs[DD];
    float hc[DD];
    float lw[HH][HH];      // [wave][head] l partials
    float redf[16];
    float redv[8];
    int   redi[8];
    float Mh[HH];
    float stat[2];
    int   cur;
    float rbv;
};

__global__ __launch_bounds__(512)
void decoder(const float* __restrict__ E, const float* __restrict__ Ws,
             const float* __restrict__ Wn, const float* __restrict__ fc,
             const float* __restrict__ Wog, const float* __restrict__ WkT,
             float* __restrict__ out_logp, float* __restrict__ out_seq, int T) {
    __shared__ SMw sm;
    const int b = blockIdx.x, tid = threadIdx.x;
    const int lane = tid & 63, wv = tid >> 6;     // 8 waves
    const int g4 = tid >> 7, d128 = tid & 127;
    const int n = tid;                            // this thread's row
    const float* Eb = E + (size_t)b * NN * DD;
    const float4* Ef4 = (const float4*)Eb;

    // ---- init: fill Ehi (hi half, swizzled) coalesced; load lo half to regs ----
    #pragma unroll
    for (int i = 0; i < 16; ++i) {
        int f = i * 512 + tid;
        int nn = f >> 4, c = f & 15;
        *(float4*)&sm.Ehi[nn * 64 + ((c ^ (nn & 15)) << 2)] = Ef4[nn * 32 + 16 + c];
    }
    float4 e0, e1, e2, e3, e4, e5, e6, e7, e8, e9, e10, e11, e12, e13, e14, e15;
#define LD(q) e##q = Ef4[n * 32 + q];
    FOR16(LD)
#undef LD
    bool vis = false;
    if (tid < DD) sm.fcs[tid] = fc[b * DD + tid];
    __syncthreads();
    // Rb = max_n ||E[n]||
    {
        float s = 0.f;
#define NRM(q) s += dot4(e##q, e##q);
        FOR16(NRM)
#undef NRM
        const int nm = n & 15;
        #pragma unroll
        for (int c = 0; c < 16; ++c) {
            float4 v = *(const float4*)&sm.Ehi[n * 64 + ((c ^ nm) << 2)];
            s += dot4(v, v);
        }
        for (int o = 1; o < 64; o <<= 1) s = fmaxf(s, __shfl_xor(s, o));
        if (lane == 0) sm.redf[wv] = s;
    }
    if (tid == 0) sm.cur = 0;
    if (n == 0) {
#define WC(q) *(float4*)&sm.curE[4 * (q)] = e##q;
        FOR16(WC)
#undef WC
    }
    __syncthreads();
    if (tid == 0) {
        float m = sm.redf[0];
        for (int i = 1; i < 8; ++i) m = fmaxf(m, sm.redf[i]);
        sm.rbv = sqrtf(m);
    }
    __syncthreads();

    float* const lgp = &sm.part[0][0];
    float* const pw  = &sm.P[0][0];

    for (int t = 0; t < T; ++t) {
        // ---- phase 0: q = fc + E[cur]@Ws + frac*Ws_last (4 k-groups of 32) ----
        {
            float s = 0.f;
            const float* Wsg = Ws + d128;
            const int cu = sm.cur, cm = cu & 15;
            if (g4 < 2) {
                int k0 = g4 * 32;
                #pragma unroll 8
                for (int k = k0; k < k0 + 32; ++k) s += sm.curE[k] * Wsg[k * DD];
            } else {
                int k0 = g4 * 32;
                #pragma unroll 8
                for (int k = k0; k < k0 + 32; ++k) {
                    int qd = (k >> 2) - 16;
                    float ek = sm.Ehi[cu * 64 + ((qd ^ cm) << 2) + (k & 3)];
                    s += ek * Wsg[k * DD];
                }
                if (g4 == 3) s += ((float)t / (float)T) * Wsg[DD * DD];
            }
            sm.part[g4][d128] = s;
        }
        __syncthreads();
        if (tid < DD)
            sm.qarr[tid] = sm.fcs[tid] + sm.part[0][tid] + sm.part[1][tid]
                         + sm.part[2][tid] + sm.part[3][tid];
        __syncthreads();
        // ---- phase 0b: qt (0.25 folded) + Cauchy-Schwarz safe max ----
        {
            const int hA = g4, hB = g4 + 4;
            const float* WA = WkT + (hA * 16) * DD + d128;
            const float* WB = WkT + (hB * 16) * DD + d128;
            float a = 0.f, c = 0.f;
            #pragma unroll
            for (int j = 0; j < 16; ++j) {
                a += sm.qarr[hA * 16 + j] * WA[j * DD];
                c += sm.qarr[hB * 16 + j] * WB[j * DD];
            }
            a *= 0.25f; c *= 0.25f;
            sm.qt[hA][d128] = a;
            sm.qt[hB][d128] = c;
            float sa = a * a, sc = c * c;
            for (int o = 1; o < 64; o <<= 1) {
                sa += __shfl_xor(sa, o);
                sc += __shfl_xor(sc, o);
            }
            if (lane == 0) { sm.redf[wv] = sa; sm.redf[8 + wv] = sc; }
        }
        __syncthreads();
        if (tid < 8) {
            int h = tid;
            float ss = (h < 4) ? (sm.redf[2 * h] + sm.redf[2 * h + 1])
                               : (sm.redf[8 + 2 * (h - 4)] + sm.redf[8 + 2 * (h - 4) + 1]);
            sm.Mh[h] = sqrtf(ss) * sm.rbv;
        }
        __syncthreads();

        // ---- compat: q-outer / h-inner, 8 named accumulators; E touched once ----
        {
            float s0 = 0.f, s1 = 0.f, s2 = 0.f, s3 = 0.f,
                  s4 = 0.f, s5 = 0.f, s6 = 0.f, s7 = 0.f;
#define CQH(j, EV) { float4 ev_ = (EV); \
            s0 += dot4(*(const float4*)&sm.qt[0][4 * (j)], ev_); \
            s1 += dot4(*(const float4*)&sm.qt[1][4 * (j)], ev_); \
            s2 += dot4(*(const float4*)&sm.qt[2][4 * (j)], ev_); \
            s3 += dot4(*(const float4*)&sm.qt[3][4 * (j)], ev_); \
            s4 += dot4(*(const float4*)&sm.qt[4][4 * (j)], ev_); \
            s5 += dot4(*(const float4*)&sm.qt[5][4 * (j)], ev_); \
            s6 += dot4(*(const float4*)&sm.qt[6][4 * (j)], ev_); \
            s7 += dot4(*(const float4*)&sm.qt[7][4 * (j)], ev_); }
#define CQA(q) CQH(q, e##q)
            FOR16(CQA)
#undef CQA
            const int nm = n & 15;
            #pragma unroll
            for (int j = 16; j < 32; ++j) {
                float4 ev = *(const float4*)&sm.Ehi[n * 64 + (((j - 16) ^ nm) << 2)];
                CQH(j, ev)
            }
#undef CQH
            sm.P[0][n] = vis ? 0.f : expf(s0 - sm.Mh[0]);
            sm.P[1][n] = vis ? 0.f : expf(s1 - sm.Mh[1]);
            sm.P[2][n] = vis ? 0.f : expf(s2 - sm.Mh[2]);
            sm.P[3][n] = vis ? 0.f : expf(s3 - sm.Mh[3]);
            sm.P[4][n] = vis ? 0.f : expf(s4 - sm.Mh[4]);
            sm.P[5][n] = vis ? 0.f : expf(s5 - sm.Mh[5]);
            sm.P[6][n] = vis ? 0.f : expf(s6 - sm.Mh[6]);
            sm.P[7][n] = vis ? 0.f : expf(s7 - sm.Mh[7]);
        }
        __syncthreads();

        // ---- e-bar: lanes (head, d-quad); lo from global E, hi from Ehi ----
        const int eh = lane >> 3, edq = lane & 7;
        float4 a0 = {0,0,0,0}, a1 = {0,0,0,0}, a2 = {0,0,0,0}, a3 = {0,0,0,0};
        {
            const int nb = wv * 64;
            float lacc = 0.f;
            #pragma unroll 2
            for (int i = 0; i < 64; ++i) {
                int nn = nb + i;
                float pv = sm.P[eh][nn];
                float4 g0 = Ef4[nn * 32 + edq];
                float4 g1 = Ef4[nn * 32 + edq + 8];
                int nm2 = nn & 15;
                float4 h0 = *(const float4*)&sm.Ehi[nn * 64 + ((edq ^ nm2) << 2)];
                float4 h1 = *(const float4*)&sm.Ehi[nn * 64 + (((edq + 8) ^ nm2) << 2)];
                fma4(a0, pv, g0);
                fma4(a1, pv, g1);
                fma4(a2, pv, h0);
                fma4(a3, pv, h1);
                lacc += pv;
            }
            if (edq == 0) sm.lw[wv][eh] = lacc;
        }
        __syncthreads();   // all P reads done; pw may overwrite P region
        if (wv < 4) {      // waves 0-3: write partial slots
            float* d = pw + (size_t)(wv * 8 + eh) * 128;
            *(float4*)&d[edq * 4]            = a0;
            *(float4*)&d[(edq + 8) * 4]      = a1;
            *(float4*)&d[64 + edq * 4]       = a2;
            *(float4*)&d[64 + (edq + 8) * 4] = a3;
        }
        __syncthreads();
        if (wv >= 4) {     // waves 4-7: add into slot wv-4
            float* d = pw + (size_t)((wv - 4) * 8 + eh) * 128;
            float4 t0 = *(float4*)&d[edq * 4];
            float4 t1 = *(float4*)&d[(edq + 8) * 4];
            float4 t2 = *(float4*)&d[64 + edq * 4];
            float4 t3 = *(float4*)&d[64 + (edq + 8) * 4];
            t0.x += a0.x; t0.y += a0.y; t0.z += a0.z; t0.w += a0.w;
            t1.x += a1.x; t1.y += a1.y; t1.z += a1.z; t1.w += a1.w;
            t2.x += a2.x; t2.y += a2.y; t2.z += a2.z; t2.w += a2.w;
            t3.x += a3.x; t3.y += a3.y; t3.z += a3.z; t3.w += a3.w;
            *(float4*)&d[edq * 4]            = t0;
            *(float4*)&d[(edq + 8) * 4]      = t1;
            *(float4*)&d[64 + edq * 4]       = t2;
            *(float4*)&d[64 + (edq + 8) * 4] = t3;
        }
        __syncthreads();
        {   // combine 4 slots -> eb[h][d] normalized; thread = (h, d2) x {d2, d2+64}
            int h = tid >> 6, d2 = tid & 63;
            float lsum = 0.f;
            #pragma unroll
            for (int w = 0; w < 8; ++w) lsum += sm.lw[w][h];
            float inv = 1.0f / lsum;
            #pragma unroll
            for (int r = 0; r < 2; ++r) {
                int d = d2 + r * 64;
                float a = 0.f;
                #pragma unroll
                for (int s = 0; s < 4; ++s) a += pw[(size_t)(s * 8 + h) * 128 + d];
                sm.eb[h][d] = a * inv;
            }
        }
        __syncthreads();

        // ---- phase 2: hc = eb @ Wv ; g~ = hc @ W_og ----
        {
            float s = 0.f;
            int k0 = g4 * 32;
            const int hh = d128 >> 4;
            const float* Wv = Wn + 128 + d128;
            #pragma unroll 8
            for (int d = k0; d < k0 + 32; ++d) s += sm.eb[hh][d] * Wv[d * 384];
            sm.part[g4][d128] = s;
        }
        __syncthreads();
        if (tid < DD)
            sm.hc[tid] = sm.part[0][tid] + sm.part[1][tid] + sm.part[2][tid] + sm.part[3][tid];
        __syncthreads();
        {
            float s = 0.f;
            int k0 = g4 * 32;
            #pragma unroll 8
            for (int k = k0; k < k0 + 32; ++k) s += sm.hc[k] * Wog[k * DD + d128];
            sm.part[g4][d128] = s;
        }
        __syncthreads();
        if (tid < DD)
            sm.qarr[tid] = (sm.part[0][tid] + sm.part[1][tid] + sm.part[2][tid]
                          + sm.part[3][tid]) * INV_SQRT_D;   // qarr reused as g~
        __syncthreads();

        // ---- logits: q-outer from regs + Ehi (overwrites part region as lgp) ----
        {
            float s = 0.f;
#define GQA(q) s += dot4(*(const float4*)&sm.qarr[4 * (q)], e##q);
            FOR16(GQA)
#undef GQA
            const int nm = n & 15;
            #pragma unroll
            for (int j = 16; j < 32; ++j) {
                float4 ev = *(const float4*)&sm.Ehi[n * 64 + (((j - 16) ^ nm) << 2)];
                s += dot4(*(const float4*)&sm.qarr[4 * j], ev);
            }
            float lg = vis ? NEGC : 10.0f * tanhf(s);
            __syncthreads();                 // part (phase2) dead -> safe to alias
            lgp[n] = lg;
        }
        __syncthreads();

        // ---- phase 4: log_softmax + write + argmax (first-index ties) + update ----
        {
            float x = lgp[tid];
            float m = x;
            for (int o = 1; o < 64; o <<= 1) m = fmaxf(m, __shfl_xor(m, o));
            if (lane == 0) sm.redf[wv] = m;
            __syncthreads();
            if (tid == 0) {
                float mm = sm.redf[0];
                for (int i = 1; i < 8; ++i) mm = fmaxf(mm, sm.redf[i]);
                sm.stat[0] = mm;
            }
            __syncthreads();
            float mm = sm.stat[0];
            float sh = x - mm;                 // masked: -1e9 - mm rounds to -1e9
            float ex = expf(sh);               // masked: exactly 0
            float ssum = ex;
            for (int o = 1; o < 64; o <<= 1) ssum += __shfl_xor(ssum, o);
            if (lane == 0) sm.redf[wv] = ssum;
            __syncthreads();
            if (tid == 0) {
                float s8 = 0.f;
                for (int i = 0; i < 8; ++i) s8 += sm.redf[i];
                sm.stat[1] = logf(s8);
            }
            __syncthreads();
            float lse = sm.stat[1];
            float lp = sh - lse;
            out_logp[((size_t)b * T + t) * NN + tid] = lp;
            float bv = lp; int bi = tid;
            for (int o = 1; o < 64; o <<= 1) {
                float ov = __shfl_xor(bv, o);
                int   oi = __shfl_xor(bi, o);
                if (ov > bv || (ov == bv && oi < bi)) { bv = ov; bi = oi; }
            }
            if (lane == 0) { sm.redv[wv] = bv; sm.redi[wv] = bi; }
            __syncthreads();
            if (tid == 0) {
                float best = sm.redv[0]; int besti = sm.redi[0];
                for (int i = 1; i < 8; ++i) {
                    float ov = sm.redv[i]; int oi = sm.redi[i];
                    if (ov > best || (ov == best && oi < besti)) { best = ov; besti = oi; }
                }
                sm.cur = besti;
                out_seq[(size_t)b * T + t] = (float)besti;
            }
            __syncthreads();
            if (n == sm.cur) {                 // winner row -> curE lo; mark visited
                vis = true;
#define WC(q) *(float4*)&sm.curE[4 * (q)] = e##q;
                FOR16(WC)
#undef WC
            }
            __syncthreads();
        }
    }
}

// ------------------------------- launcher -----------------------------------
extern "C" void kernel_launch(void* const* d_in, const int* in_sizes, int n_in,
                              void* d_out, int out_size, void* d_ws, size_t ws_size,
                              hipStream_t stream) {
    const float* E    = (const float*)d_in[0];   // [B,N,D]
    const float* Wn   = (const float*)d_in[1];   // [D,3D]
    const float* Wf   = (const float*)d_in[2];   // [D,D]
    const float* Ws   = (const float*)d_in[3];   // [D+1,D]
    const float* Wout = (const float*)d_in[4];   // [D,D]
    float* out = (float*)d_out;

    const int T = out_size / (BB * (NN + 1));    // = num_steps (64)

    float* fc  = (float*)d_ws;                   // [B,D]
    float* Wog = fc + BB * DD;                   // [128,128]
    float* WkT = Wog + DD * DD;                  // [128,128]

    precompute_fc<<<BB, 128, 0, stream>>>(E, Wf, fc);
    precompute_w<<<DD, 128, 0, stream>>>(Wn, Wout, Wog, WkT);
    decoder<<<BB, 512, 0, stream>>>(E, Ws, Wn, fc, Wog, WkT,
                                    out, out + (size_t)BB * T * NN, T);
}

// Round 9
// 3318.873 us; speedup vs baseline: 4.2906x; 4.2906x over previous
//
#include <hip/hip_runtime.h>

#define BB 256
#define NN 512
#define DD 128
#define HH 8

static constexpr float NEGC = -1e9f;
static constexpr float INV_SQRT_D = 0.08838834764831845f; // 1/sqrt(128)

typedef float fv16 __attribute__((ext_vector_type(16)));

__device__ __forceinline__ float dot4(float4 a, float4 b) {
    return a.x * b.x + a.y * b.y + a.z * b.z + a.w * b.w;
}

// Force a (wave-uniform) pointer into SGPRs so "s" asm constraints are valid.
__device__ __forceinline__ const float* uniform_ptr(const float* p) {
    unsigned long long a = (unsigned long long)p;
    unsigned int lo = __builtin_amdgcn_readfirstlane((unsigned int)a);
    unsigned int hi = __builtin_amdgcn_readfirstlane((unsigned int)(a >> 32));
    return (const float*)(((unsigned long long)hi << 32) | lo);
}

// 64 consecutive floats from a wave-uniform global address -> 4 SGPR x16 tuples.
#define SLOAD64(q0_, q1_, q2_, q3_, base_)                          \
    asm volatile("s_load_dwordx16 %0, %4, 0x0\n\t"                  \
                 "s_load_dwordx16 %1, %4, 0x40\n\t"                 \
                 "s_load_dwordx16 %2, %4, 0x80\n\t"                 \
                 "s_load_dwordx16 %3, %4, 0xc0\n\t"                 \
                 "s_waitcnt lgkmcnt(0)"                             \
                 : "=s"(q0_), "=s"(q1_), "=s"(q2_), "=s"(q3_)       \
                 : "s"(base_))

#define DCACHE_INV() asm volatile("s_dcache_inv" ::: "memory")

// ---------------- precompute: fixed_ctx = mean_n(E) @ W_fixed ----------------
__global__ __launch_bounds__(128)
void precompute_fc(const float* __restrict__ E, const float* __restrict__ Wf,
                   float* __restrict__ fc) {
    int b = blockIdx.x, d = threadIdx.x;
    __shared__ float ge[DD];
    const float* Eb = E + (size_t)b * NN * DD;
    float s = 0.f;
    for (int n = 0; n < NN; ++n) s += Eb[n * DD + d];
    ge[d] = s * (1.0f / 512.0f);
    __syncthreads();
    float o = 0.f;
    for (int k = 0; k < DD; ++k) o += ge[k] * Wf[k * DD + d];
    fc[b * DD + d] = o;
}

// ---- precompute: WkT[k][d] = W_node[d][k] (k<128);  W_og = W_out @ Wl^T ----
__global__ __launch_bounds__(128)
void precompute_w(const float* __restrict__ Wn, const float* __restrict__ Wout,
                  float* __restrict__ Wog, float* __restrict__ WkT) {
    int k = blockIdx.x, d = threadIdx.x;
    WkT[k * DD + d] = Wn[d * 384 + k];
    float s = 0.f;
    for (int e = 0; e < DD; ++e) s += Wout[k * DD + e] * Wn[d * 384 + 256 + e];
    Wog[k * DD + d] = s;
}

// ---------------------------- main decoder ----------------------------------
// 512 threads (VGPR budget 65536/512 = 128; working set ~30 -> no spill).
// E-lo (d<64) in LDS (swizzled q^(n&15)); E-hi from global. qt/P/g~ round-trip
// through d_ws; read back via s_load -> SGPR tuples (vector L1 is write-through,
// barrier drains to L2, s_dcache_inv before scalar reads).
struct SMx {
    float EA[NN * 64];      // 131072 B
    float SCR[4096];        // 16384 B: e-bar partials [4][8][128] / p2 [4][128]
    float part[4][DD];      // 2048 B: phase0/2 partials; lgp[512] alias
    float eb[HH][DD];       // 4096 B
    float curE[DD];
    float qarr[DD];
    float fcs[DD];
    float hc[DD];
    float l[HH];
    float Mh[HH];
    float redf[16];
    float redv[8];
    int   redi[8];
    float stat[2];
    int   cur;
    float rbv;
};

__global__ __launch_bounds__(512)
void decoder(const float* __restrict__ E, const float* __restrict__ Ws,
             const float* __restrict__ Wn, const float* __restrict__ fc,
             const float* __restrict__ Wog, const float* __restrict__ WkT,
             float* __restrict__ qtT_all, float* __restrict__ Pg_all,
             float* __restrict__ out_logp, float* __restrict__ out_seq, int T) {
    __shared__ SMx sm;
    const int b = blockIdx.x, tid = threadIdx.x;
    const int lane = tid & 63, wv = tid >> 6;
    const int g4 = tid >> 7, d128 = tid & 127;
    const int n = tid;
    const float* Eg = E + (size_t)b * NN * DD;
    const float4* Ef4 = (const float4*)Eg;
    float* qtT_b = qtT_all + (size_t)b * 1024;   // [128 dims][8 heads]; [0..127] reused for g~
    float* Pg_b  = Pg_all  + (size_t)b * 4096;   // [512 rows][8 heads]

    // ---- init: EA (lo half, swizzled), fcs, curE(row0), rbv ----
    #pragma unroll
    for (int i = 0; i < 16; ++i) {
        int f = i * 512 + tid;
        int nn2 = f >> 4, c = f & 15;
        *(float4*)&sm.EA[nn2 * 64 + ((c ^ (nn2 & 15)) << 2)] = Ef4[nn2 * 32 + c];
    }
    bool vis = false;
    if (tid < DD) sm.fcs[tid] = fc[b * DD + tid];
    if (tid < DD) sm.curE[tid] = Eg[tid];
    if (tid == 0) sm.cur = 0;
    {
        float s = 0.f;
        #pragma unroll 8
        for (int i = 0; i < 32; ++i) { float4 v = Ef4[tid * 32 + i]; s += dot4(v, v); }
        for (int o = 1; o < 64; o <<= 1) s = fmaxf(s, __shfl_xor(s, o));
        if (lane == 0) sm.redf[wv] = s;
    }
    __syncthreads();
    if (tid == 0) {
        float m = sm.redf[0];
        for (int i = 1; i < 8; ++i) m = fmaxf(m, sm.redf[i]);
        sm.rbv = sqrtf(m);
    }
    __syncthreads();

    float* const lgp = &sm.part[0][0];

    for (int t = 0; t < T; ++t) {
        // ---- phase 0: q = fc + E[cur]@Ws + frac*Ws_last ----
        {
            float s = 0.f;
            const float* Wsg = Ws + d128;
            int k0 = g4 * 32;
            #pragma unroll 8
            for (int k = k0; k < k0 + 32; ++k) s += sm.curE[k] * Wsg[k * DD];
            if (g4 == 3) s += ((float)t / (float)T) * Wsg[DD * DD];
            sm.part[g4][d128] = s;
        }
        __syncthreads();
        if (tid < DD)
            sm.qarr[tid] = sm.fcs[tid] + sm.part[0][tid] + sm.part[1][tid]
                         + sm.part[2][tid] + sm.part[3][tid];
        __syncthreads();
        // ---- phase 0b: qt (0.25 folded) -> qtT global [d][h]; Cauchy-Schwarz Mh ----
        {
            const int hA = g4, hB = g4 + 4;
            const float* WA = WkT + (hA * 16) * DD + d128;
            const float* WB = WkT + (hB * 16) * DD + d128;
            float a = 0.f, c = 0.f;
            #pragma unroll
            for (int j = 0; j < 16; ++j) {
                a += sm.qarr[hA * 16 + j] * WA[j * DD];
                c += sm.qarr[hB * 16 + j] * WB[j * DD];
            }
            a *= 0.25f; c *= 0.25f;
            qtT_b[d128 * 8 + hA] = a;
            qtT_b[d128 * 8 + hB] = c;
            float sa = a * a, sc = c * c;
            for (int o = 1; o < 64; o <<= 1) {
                sa += __shfl_xor(sa, o);
                sc += __shfl_xor(sc, o);
            }
            if (lane == 0) { sm.redf[wv] = sa; sm.redf[8 + wv] = sc; }
        }
        __syncthreads();   // drains qtT stores to L2
        if (tid < 8) {
            int h = tid;
            float ss = (h < 4) ? (sm.redf[2 * h] + sm.redf[2 * h + 1])
                               : (sm.redf[8 + 2 * (h - 4)] + sm.redf[8 + 2 * (h - 4) + 1]);
            sm.Mh[h] = sqrtf(ss) * sm.rbv;
        }
        __syncthreads();
        DCACHE_INV();

        // ---- compat: full row per thread; qt from SGPRs; lo LDS / hi global ----
        {
            const float* qtb = uniform_ptr(qtT_b);
            const int nm = n & 15;
            float a0 = 0.f, a1 = 0.f, a2 = 0.f, a3 = 0.f,
                  a4 = 0.f, a5 = 0.f, a6 = 0.f, a7 = 0.f;
            fv16 q0_, q1_, q2_, q3_;
            float4 u, v;
#define CT(h_) a##h_ += q0_[h_] * u.x + q0_[8 + h_] * u.y + q1_[h_] * u.z + q1_[8 + h_] * u.w \
                      + q2_[h_] * v.x + q2_[8 + h_] * v.y + q3_[h_] * v.z + q3_[8 + h_] * v.w;
#define CGRP(o_, UU, VV) { SLOAD64(q0_, q1_, q2_, q3_, qtb + (o_) * 64); \
            u = (UU); v = (VV); CT(0) CT(1) CT(2) CT(3) CT(4) CT(5) CT(6) CT(7) }
#define EAQ(q_) (*(const float4*)&sm.EA[n * 64 + (((q_) ^ nm) << 2)])
            CGRP(0,  EAQ(0),  EAQ(1))  CGRP(1,  EAQ(2),  EAQ(3))
            CGRP(2,  EAQ(4),  EAQ(5))  CGRP(3,  EAQ(6),  EAQ(7))
            CGRP(4,  EAQ(8),  EAQ(9))  CGRP(5,  EAQ(10), EAQ(11))
            CGRP(6,  EAQ(12), EAQ(13)) CGRP(7,  EAQ(14), EAQ(15))
            CGRP(8,  Ef4[n * 32 + 16], Ef4[n * 32 + 17])
            CGRP(9,  Ef4[n * 32 + 18], Ef4[n * 32 + 19])
            CGRP(10, Ef4[n * 32 + 20], Ef4[n * 32 + 21])
            CGRP(11, Ef4[n * 32 + 22], Ef4[n * 32 + 23])
            CGRP(12, Ef4[n * 32 + 24], Ef4[n * 32 + 25])
            CGRP(13, Ef4[n * 32 + 26], Ef4[n * 32 + 27])
            CGRP(14, Ef4[n * 32 + 28], Ef4[n * 32 + 29])
            CGRP(15, Ef4[n * 32 + 30], Ef4[n * 32 + 31])
#undef EAQ
#undef CGRP
#undef CT
            float4 P0, P1;
            P0.x = vis ? 0.f : expf(a0 - sm.Mh[0]);
            P0.y = vis ? 0.f : expf(a1 - sm.Mh[1]);
            P0.z = vis ? 0.f : expf(a2 - sm.Mh[2]);
            P0.w = vis ? 0.f : expf(a3 - sm.Mh[3]);
            P1.x = vis ? 0.f : expf(a4 - sm.Mh[4]);
            P1.y = vis ? 0.f : expf(a5 - sm.Mh[5]);
            P1.z = vis ? 0.f : expf(a6 - sm.Mh[6]);
            P1.w = vis ? 0.f : expf(a7 - sm.Mh[7]);
            *(float4*)(Pg_b + n * 8)     = P0;
            *(float4*)(Pg_b + n * 8 + 4) = P1;
        }
        __syncthreads();   // drains P stores to L2
        DCACHE_INV();

        // ---- l[h] (wave h, vector loads) + e-bar (P from SGPRs) ----
        {
            const int h = wv;
            float sl = 0.f;
            #pragma unroll
            for (int i = 0; i < 8; ++i) sl += Pg_b[(lane + i * 64) * 8 + h];
            for (int o = 1; o < 64; o <<= 1) sl += __shfl_xor(sl, o);
            if (lane == 0) sm.l[h] = sl;
        }
        {
            const int rg = tid >> 7, dd = tid & 127;
            const float* pb = uniform_ptr(Pg_b + rg * 1024);
            const int r0b = rg * 128;
            float c0 = 0.f, c1 = 0.f, c2 = 0.f, c3 = 0.f,
                  c4 = 0.f, c5 = 0.f, c6 = 0.f, c7 = 0.f;
            fv16 p0_, p1_, p2_, p3_;
#define ACC(T_, B_, EV_) { float ev_ = (EV_);                                   \
            c0 += T_[(B_) + 0] * ev_; c1 += T_[(B_) + 1] * ev_;                  \
            c2 += T_[(B_) + 2] * ev_; c3 += T_[(B_) + 3] * ev_;                  \
            c4 += T_[(B_) + 4] * ev_; c5 += T_[(B_) + 5] * ev_;                  \
            c6 += T_[(B_) + 6] * ev_; c7 += T_[(B_) + 7] * ev_; }
#define ELDSV(k_) sm.EA[(r0 + k_) * 64 + ((((dd >> 2) ^ ((r0 + k_) & 15))) << 2) + (dd & 3)]
#define EGLBV(k_) Eg[(r0 + k_) * 128 + dd]
#define EB8(EVM)                                                                \
            for (int g = 0; g < 16; ++g) {                                      \
                SLOAD64(p0_, p1_, p2_, p3_, pb + g * 64);                       \
                const int r0 = r0b + g * 8;                                     \
                ACC(p0_, 0, EVM(0)) ACC(p0_, 8, EVM(1))                         \
                ACC(p1_, 0, EVM(2)) ACC(p1_, 8, EVM(3))                         \
                ACC(p2_, 0, EVM(4)) ACC(p2_, 8, EVM(5))                         \
                ACC(p3_, 0, EVM(6)) ACC(p3_, 8, EVM(7))                         \
            }
            if (dd < 64) { EB8(ELDSV) } else { EB8(EGLBV) }
#undef EB8
#undef EGLBV
#undef ELDSV
#undef ACC
            sm.SCR[(rg * 8 + 0) * 128 + dd] = c0;
            sm.SCR[(rg * 8 + 1) * 128 + dd] = c1;
            sm.SCR[(rg * 8 + 2) * 128 + dd] = c2;
            sm.SCR[(rg * 8 + 3) * 128 + dd] = c3;
            sm.SCR[(rg * 8 + 4) * 128 + dd] = c4;
            sm.SCR[(rg * 8 + 5) * 128 + dd] = c5;
            sm.SCR[(rg * 8 + 6) * 128 + dd] = c6;
            sm.SCR[(rg * 8 + 7) * 128 + dd] = c7;
        }
        __syncthreads();
        {   // combine 4 rg-partials -> eb[h][d] normalized
            const int h = tid >> 6, d2 = (tid & 63) * 2;
            float inv = 1.0f / sm.l[h];
            #pragma unroll
            for (int r = 0; r < 2; ++r) {
                int d = d2 + r;
                float a = sm.SCR[(0 * 8 + h) * 128 + d] + sm.SCR[(1 * 8 + h) * 128 + d]
                        + sm.SCR[(2 * 8 + h) * 128 + d] + sm.SCR[(3 * 8 + h) * 128 + d];
                sm.eb[h][d] = a * inv;
            }
        }
        __syncthreads();

        // ---- phase 2: hc = eb @ Wv ; g~ = hc @ W_og -> global ----
        {
            float s = 0.f;
            int k0 = g4 * 32;
            const int hh = d128 >> 4;
            const float* Wv = Wn + 128 + d128;
            #pragma unroll 8
            for (int d = k0; d < k0 + 32; ++d) s += sm.eb[hh][d] * Wv[d * 384];
            sm.part[g4][d128] = s;
        }
        __syncthreads();
        if (tid < DD)
            sm.hc[tid] = sm.part[0][tid] + sm.part[1][tid] + sm.part[2][tid] + sm.part[3][tid];
        __syncthreads();
        {
            float s = 0.f;
            int k0 = g4 * 32;
            #pragma unroll 8
            for (int k = k0; k < k0 + 32; ++k) s += sm.hc[k] * Wog[k * DD + d128];
            sm.SCR[g4 * 128 + d128] = s;
        }
        __syncthreads();
        if (tid < DD)
            qtT_b[tid] = (sm.SCR[0 * 128 + tid] + sm.SCR[1 * 128 + tid]
                        + sm.SCR[2 * 128 + tid] + sm.SCR[3 * 128 + tid]) * INV_SQRT_D;
        __syncthreads();   // drains g~ store
        DCACHE_INV();

        // ---- logits: g~ from SGPRs; lo LDS / hi global ----
        {
            const float* gb = uniform_ptr(qtT_b);
            const int nm = n & 15;
            float s = 0.f;
            fv16 g0_, g1_, g2_, g3_;
#define LQ(q_, T_, B_, EV) { float4 u = (EV);                                  \
            s += T_[(B_) + 0] * u.x + T_[(B_) + 1] * u.y                        \
               + T_[(B_) + 2] * u.z + T_[(B_) + 3] * u.w; }
#define EAQ(q_) (*(const float4*)&sm.EA[n * 64 + (((q_) ^ nm) << 2)])
            SLOAD64(g0_, g1_, g2_, g3_, gb);
            LQ(0,  g0_, 0,  EAQ(0))  LQ(1,  g0_, 4,  EAQ(1))
            LQ(2,  g0_, 8,  EAQ(2))  LQ(3,  g0_, 12, EAQ(3))
            LQ(4,  g1_, 0,  EAQ(4))  LQ(5,  g1_, 4,  EAQ(5))
            LQ(6,  g1_, 8,  EAQ(6))  LQ(7,  g1_, 12, EAQ(7))
            LQ(8,  g2_, 0,  EAQ(8))  LQ(9,  g2_, 4,  EAQ(9))
            LQ(10, g2_, 8,  EAQ(10)) LQ(11, g2_, 12, EAQ(11))
            LQ(12, g3_, 0,  EAQ(12)) LQ(13, g3_, 4,  EAQ(13))
            LQ(14, g3_, 8,  EAQ(14)) LQ(15, g3_, 12, EAQ(15))
            SLOAD64(g0_, g1_, g2_, g3_, gb + 64);
            LQ(16, g0_, 0,  Ef4[n * 32 + 16]) LQ(17, g0_, 4,  Ef4[n * 32 + 17])
            LQ(18, g0_, 8,  Ef4[n * 32 + 18]) LQ(19, g0_, 12, Ef4[n * 32 + 19])
            LQ(20, g1_, 0,  Ef4[n * 32 + 20]) LQ(21, g1_, 4,  Ef4[n * 32 + 21])
            LQ(22, g1_, 8,  Ef4[n * 32 + 22]) LQ(23, g1_, 12, Ef4[n * 32 + 23])
            LQ(24, g2_, 0,  Ef4[n * 32 + 24]) LQ(25, g2_, 4,  Ef4[n * 32 + 25])
            LQ(26, g2_, 8,  Ef4[n * 32 + 26]) LQ(27, g2_, 12, Ef4[n * 32 + 27])
            LQ(28, g3_, 0,  Ef4[n * 32 + 28]) LQ(29, g3_, 4,  Ef4[n * 32 + 29])
            LQ(30, g3_, 8,  Ef4[n * 32 + 30]) LQ(31, g3_, 12, Ef4[n * 32 + 31])
#undef EAQ
#undef LQ
            float lg = vis ? NEGC : 10.0f * tanhf(s);
            lgp[n] = lg;
        }
        __syncthreads();

        // ---- phase 4: log_softmax + write + argmax (first-index ties) ----
        {
            float x = lgp[tid];
            float m = x;
            for (int o = 1; o < 64; o <<= 1) m = fmaxf(m, __shfl_xor(m, o));
            if (lane == 0) sm.redf[wv] = m;
            __syncthreads();
            if (tid == 0) {
                float mm = sm.redf[0];
                for (int i = 1; i < 8; ++i) mm = fmaxf(mm, sm.redf[i]);
                sm.stat[0] = mm;
            }
            __syncthreads();
            float mm = sm.stat[0];
            float sh = x - mm;                 // masked: -1e9 - mm rounds to -1e9
            float ex = expf(sh);               // masked: exactly 0
            float ssum = ex;
            for (int o = 1; o < 64; o <<= 1) ssum += __shfl_xor(ssum, o);
            if (lane == 0) sm.redf[wv] = ssum;
            __syncthreads();
            if (tid == 0) {
                float s8 = 0.f;
                for (int i = 0; i < 8; ++i) s8 += sm.redf[i];
                sm.stat[1] = logf(s8);
            }
            __syncthreads();
            float lse = sm.stat[1];
            float lp = sh - lse;
            out_logp[((size_t)b * T + t) * NN + tid] = lp;
            float bv = lp; int bi = tid;
            for (int o = 1; o < 64; o <<= 1) {
                float ov = __shfl_xor(bv, o);
                int   oi = __shfl_xor(bi, o);
                if (ov > bv || (ov == bv && oi < bi)) { bv = ov; bi = oi; }
            }
            if (lane == 0) { sm.redv[wv] = bv; sm.redi[wv] = bi; }
            __syncthreads();
            if (tid == 0) {
                float best = sm.redv[0]; int besti = sm.redi[0];
                for (int i = 1; i < 8; ++i) {
                    float ov = sm.redv[i]; int oi = sm.redi[i];
                    if (ov > best || (ov == best && oi < besti)) { best = ov; besti = oi; }
                }
                sm.cur = besti;
                out_seq[(size_t)b * T + t] = (float)besti;
            }
            __syncthreads();
            {   // refresh curE (lo from LDS, hi from global); visited update
                const int cu = sm.cur;
                if (tid < DD) {
                    float vv;
                    if (tid < 64)
                        vv = sm.EA[cu * 64 + ((((tid >> 2) ^ (cu & 15))) << 2) + (tid & 3)];
                    else
                        vv = Eg[cu * DD + tid];
                    sm.curE[tid] = vv;
                }
                if (tid == cu) vis = true;
            }
            __syncthreads();
        }
    }
}

// ------------------------------- launcher -----------------------------------
extern "C" void kernel_launch(void* const* d_in, const int* in_sizes, int n_in,
                              void* d_out, int out_size, void* d_ws, size_t ws_size,
                              hipStream_t stream) {
    const float* E    = (const float*)d_in[0];   // [B,N,D]
    const float* Wn   = (const float*)d_in[1];   // [D,3D]
    const float* Wf   = (const float*)d_in[2];   // [D,D]
    const float* Ws   = (const float*)d_in[3];   // [D+1,D]
    const float* Wout = (const float*)d_in[4];   // [D,D]
    float* out = (float*)d_out;

    const int T = out_size / (BB * (NN + 1));    // = num_steps (64)

    float* fc   = (float*)d_ws;                  // [B,D]        32768 f
    float* Wog  = fc + BB * DD;                  // [128,128]    16384 f
    float* WkT  = Wog + DD * DD;                 // [128,128]    16384 f
    float* qtT  = WkT + DD * DD;                 // [B,128,8]    262144 f
    float* Pg   = qtT + (size_t)BB * 1024;       // [B,512,8]    1048576 f

    precompute_fc<<<BB, 128, 0, stream>>>(E, Wf, fc);
    precompute_w<<<DD, 128, 0, stream>>>(Wn, Wout, Wog, WkT);
    decoder<<<BB, 512, 0, stream>>>(E, Ws, Wn, fc, Wog, WkT, qtT, Pg,
                                    out, out + (size_t)BB * T * NN, T);
}